// Round 1
// 373.129 us; speedup vs baseline: 1.0934x; 1.0934x over previous
//
#include <hip/hip_runtime.h>
#include <hip/hip_bf16.h>
#include <cmath>

#define D_MODEL 1024
#define NHEADS  16
#define DK      64
#define BATCH   32
#define SEQ     512
#define M_TOTAL (BATCH * SEQ)   // 16384
#define LIN_EPS 1e-6f

typedef __attribute__((ext_vector_type(8))) short short8;
typedef __attribute__((ext_vector_type(4))) short short4v;
typedef __attribute__((ext_vector_type(4))) float floatx4;

__device__ inline short f2bf(float f) {
    __hip_bfloat16 h = __float2bfloat16(f);
    return *reinterpret_cast<short*>(&h);
}
__device__ inline float bf2f(short s) {
    unsigned int u = ((unsigned int)(unsigned short)s) << 16;
    union { unsigned int u; float f; } c; c.u = u;
    return c.f;
}

#define GLL16(gptr, lptr)                                                      \
    __builtin_amdgcn_global_load_lds(                                          \
        (const __attribute__((address_space(1))) unsigned int*)(gptr),         \
        (__attribute__((address_space(3))) unsigned int*)(lptr), 16, 0, 0)

// ---------------------------------------------------------------------------
// fp32 -> bf16 cast
// ---------------------------------------------------------------------------
__global__ __launch_bounds__(256)
void cast_bf16(const float* __restrict__ in, short* __restrict__ out, int n4)
{
    int i = blockIdx.x * 256 + threadIdx.x;
    if (i >= n4) return;
    float4 f = *(const float4*)&in[(size_t)i * 4];
    short4v s;
    s.x = f2bf(f.x); s.y = f2bf(f.y); s.z = f2bf(f.z); s.w = f2bf(f.w);
    *(short4v*)&out[(size_t)i * 4] = s;
}

// ---------------------------------------------------------------------------
// All four W[K][N] fp32 -> Wt[N][K] bf16; z selects matrix.
// ---------------------------------------------------------------------------
__global__ __launch_bounds__(256)
void transpose_w4(const float* __restrict__ W0, const float* __restrict__ W1,
                  const float* __restrict__ W2, const float* __restrict__ W3,
                  short* __restrict__ WtBase)
{
    __shared__ float tile[32][33];
    const int z = blockIdx.z;
    const float* W = (z == 0) ? W0 : (z == 1) ? W1 : (z == 2) ? W2 : W3;
    short* Wt = WtBase + (size_t)z * D_MODEL * D_MODEL;
    const int tx = threadIdx.x, ty = threadIdx.y;   // 32 x 8
    const int nb = blockIdx.x * 32, kb = blockIdx.y * 32;
    #pragma unroll
    for (int r = 0; r < 32; r += 8)
        tile[ty + r][tx] = W[(size_t)(kb + ty + r) * D_MODEL + nb + tx];
    __syncthreads();
    #pragma unroll
    for (int r = 0; r < 32; r += 8)
        Wt[(size_t)(nb + ty + r) * D_MODEL + kb + tx] = f2bf(tile[tx][ty + r]);
}

// ---------------------------------------------------------------------------
// 256x256 8-phase GEMM (HK-style T1+T2+T3+T4+T5 in plain HIP).
//   BM=BN=256, BK=64 as 2 k-halves of 32. 512 threads = 8 waves (2M x 4N).
//   LDS 128 KiB: 2 bufs x {A,B} x {k0,k1} of [256 rows][32 k] bf16.
//   Per K-tile: 4 phases x 16 MFMA; each phase stages one k-half of tile t+1.
//   vmcnt(4) at phases 2 & 4 only (provably retires exactly the k-halves
//   consumed next; 4 loads always in flight; never drains in main loop).
//   T2 swizzle: LDS slot' = slot ^ ((row>>1)&3), inverse applied to global
//   source (global_load_lds dest stays linear, rule 21).
// MODE 0: C += bias[q|k|v]; seg<2 -> elu+1; bf16 store to [seg][B,H,N,DK].
// MODE 1: C += bias; fp32 store row-major [M][1024].
// ---------------------------------------------------------------------------
template<int MODE>
__global__ __launch_bounds__(512, 2)
void gemm256(const short* __restrict__ A, const short* __restrict__ Wt,
             const float* __restrict__ bq, const float* __restrict__ bk,
             const float* __restrict__ bv, short* __restrict__ outB,
             float* __restrict__ outF)
{
    constexpr int K   = 1024;
    constexpr int NBX = (MODE == 0) ? 12 : 4;   // col-tiles of 256
    __shared__ short lds[65536];                // 128 KiB

    const int t    = threadIdx.x;
    const int wave = t >> 6;
    const int lane = t & 63;
    const int wm   = wave >> 2;                 // 0..1  -> rows wm*128
    const int wn   = wave & 3;                  // 0..3  -> cols wn*64

    // T1: bijective XCD swizzle (nwg % 8 == 0 in both modes)
    const int nwg = NBX * 64;
    const int cpx = nwg >> 3;
    const int bid = (int)blockIdx.x;
    const int swb = (bid & 7) * cpx + (bid >> 3);
    const int by  = swb / NBX;
    const int bx  = swb % NBX;
    const int rowBase = by * 256;
    const int colBase = bx * 256;

    // fragment read addressing (T2 read-side swizzle)
    const int laneM = lane & 15;
    const int g     = lane >> 4;
    const int co    = ((g ^ ((laneM >> 1) & 3)) << 3);         // shorts
    const int aoff  = (wm * 128 + laneM) * 32 + co;            // A k0 base
    const int boff  = 16384 + (wn * 64 + laneM) * 32 + co;     // B k0 base

    // staging addressing (T2 inverse swizzle on global source)
    const int stRow = t >> 2;                                   // 0..127
    const int stCol = (((t & 3) ^ ((t >> 3) & 3)) << 3);        // shorts
    const short* aSt = A  + (size_t)(rowBase + stRow) * K + stCol;
    const short* bSt = Wt + (size_t)(colBase + stRow) * K + stCol;
    const int dT = t * 8;                                       // shorts

    floatx4 acc[8][4];
    #pragma unroll
    for (int i = 0; i < 8; i++)
        #pragma unroll
        for (int j = 0; j < 4; j++) acc[i][j] = (floatx4){0.f, 0.f, 0.f, 0.f};

    // prologue: tile 0 -> buf 0. Issue order Ak0,Bk0,Ak1,Bk1 (oldest first).
    GLL16(aSt,                    &lds[dT]);
    GLL16(aSt + (size_t)128 * K,  &lds[4096 + dT]);
    GLL16(bSt,                    &lds[16384 + dT]);
    GLL16(bSt + (size_t)128 * K,  &lds[16384 + 4096 + dT]);
    GLL16(aSt + 32,                   &lds[8192 + dT]);
    GLL16(aSt + 32 + (size_t)128 * K, &lds[8192 + 4096 + dT]);
    GLL16(bSt + 32,                   &lds[24576 + dT]);
    GLL16(bSt + 32 + (size_t)128 * K, &lds[24576 + 4096 + dT]);
    asm volatile("s_waitcnt vmcnt(4)" ::: "memory");   // Ak0,Bk0 landed
    __builtin_amdgcn_s_barrier();

    for (int kt = 0; kt < 16; ++kt) {
        const int cb = (kt & 1) << 15;     // current buffer base (shorts)
        const int nb = cb ^ 32768;
        const bool pf = (kt < 15);
        const short* aN = aSt + (size_t)(kt + 1) * 64;
        const short* bN = bSt + (size_t)(kt + 1) * 64;

        short8 a[8], b0, b1, b2, b3;

        // ---- phase 1: read A.k0 (8) + B.k0 j=0,1 (2); stage next A.k0 ----
        #pragma unroll
        for (int i = 0; i < 8; i++)
            a[i] = *(const short8*)&lds[cb + aoff + i * 512];
        b0 = *(const short8*)&lds[cb + boff];
        b1 = *(const short8*)&lds[cb + boff + 512];
        if (pf) {
            GLL16(aN,                   &lds[nb + dT]);
            GLL16(aN + (size_t)128 * K, &lds[nb + 4096 + dT]);
        }
        __builtin_amdgcn_s_barrier();
        asm volatile("s_waitcnt lgkmcnt(0)" ::: "memory");
        __builtin_amdgcn_s_setprio(1);
        #pragma unroll
        for (int i = 0; i < 8; i++) {
            acc[i][0] = __builtin_amdgcn_mfma_f32_16x16x32_bf16(a[i], b0, acc[i][0], 0, 0, 0);
            acc[i][1] = __builtin_amdgcn_mfma_f32_16x16x32_bf16(a[i], b1, acc[i][1], 0, 0, 0);
        }
        __builtin_amdgcn_s_setprio(0);
        __builtin_amdgcn_s_barrier();

        // ---- phase 2: read B.k0 j=2,3; stage next B.k0; vmcnt ----
        b2 = *(const short8*)&lds[cb + boff + 1024];
        b3 = *(const short8*)&lds[cb + boff + 1536];
        if (pf) {
            GLL16(bN,                   &lds[nb + 16384 + dT]);
            GLL16(bN + (size_t)128 * K, &lds[nb + 16384 + 4096 + dT]);
            asm volatile("s_waitcnt vmcnt(4)" ::: "memory");  // cur Ak1,Bk1 landed
        } else {
            asm volatile("s_waitcnt vmcnt(0)" ::: "memory");
        }
        __builtin_amdgcn_s_barrier();
        asm volatile("s_waitcnt lgkmcnt(0)" ::: "memory");
        __builtin_amdgcn_s_setprio(1);
        #pragma unroll
        for (int i = 0; i < 8; i++) {
            acc[i][2] = __builtin_amdgcn_mfma_f32_16x16x32_bf16(a[i], b2, acc[i][2], 0, 0, 0);
            acc[i][3] = __builtin_amdgcn_mfma_f32_16x16x32_bf16(a[i], b3, acc[i][3], 0, 0, 0);
        }
        __builtin_amdgcn_s_setprio(0);
        __builtin_amdgcn_s_barrier();

        // ---- phase 3: read A.k1 (8) + B.k1 j=0,1 (2); stage next A.k1 ----
        #pragma unroll
        for (int i = 0; i < 8; i++)
            a[i] = *(const short8*)&lds[cb + 8192 + aoff + i * 512];
        b0 = *(const short8*)&lds[cb + 8192 + boff];
        b1 = *(const short8*)&lds[cb + 8192 + boff + 512];
        if (pf) {
            GLL16(aN + 32,                   &lds[nb + 8192 + dT]);
            GLL16(aN + 32 + (size_t)128 * K, &lds[nb + 8192 + 4096 + dT]);
        }
        __builtin_amdgcn_s_barrier();
        asm volatile("s_waitcnt lgkmcnt(0)" ::: "memory");
        __builtin_amdgcn_s_setprio(1);
        #pragma unroll
        for (int i = 0; i < 8; i++) {
            acc[i][0] = __builtin_amdgcn_mfma_f32_16x16x32_bf16(a[i], b0, acc[i][0], 0, 0, 0);
            acc[i][1] = __builtin_amdgcn_mfma_f32_16x16x32_bf16(a[i], b1, acc[i][1], 0, 0, 0);
        }
        __builtin_amdgcn_s_setprio(0);
        __builtin_amdgcn_s_barrier();

        // ---- phase 4: read B.k1 j=2,3; stage next B.k1; vmcnt ----
        b2 = *(const short8*)&lds[cb + 8192 + boff + 1024];
        b3 = *(const short8*)&lds[cb + 8192 + boff + 1536];
        if (pf) {
            GLL16(bN + 32,                   &lds[nb + 24576 + dT]);
            GLL16(bN + 32 + (size_t)128 * K, &lds[nb + 24576 + 4096 + dT]);
            asm volatile("s_waitcnt vmcnt(4)" ::: "memory");  // next Ak0,Bk0 landed
        }
        __builtin_amdgcn_s_barrier();
        asm volatile("s_waitcnt lgkmcnt(0)" ::: "memory");
        __builtin_amdgcn_s_setprio(1);
        #pragma unroll
        for (int i = 0; i < 8; i++) {
            acc[i][2] = __builtin_amdgcn_mfma_f32_16x16x32_bf16(a[i], b2, acc[i][2], 0, 0, 0);
            acc[i][3] = __builtin_amdgcn_mfma_f32_16x16x32_bf16(a[i], b3, acc[i][3], 0, 0, 0);
        }
        __builtin_amdgcn_s_setprio(0);
        __builtin_amdgcn_s_barrier();
    }

    // ---------------- epilogue ----------------
    if (MODE == 0) {
        const int seg = colBase >> 10;            // 0=q 1=k 2=v (256-tiles never straddle)
        const float* bias = (seg == 0) ? bq : (seg == 1) ? bk : bv;
        short* outSeg = outB + (size_t)seg * ((size_t)M_TOTAL * D_MODEL);
        #pragma unroll
        for (int i = 0; i < 8; i++) {
            const int r0 = rowBase + wm * 128 + i * 16 + g * 4;
            #pragma unroll
            for (int j = 0; j < 4; j++) {
                const int cl = (colBase & 1023) + wn * 64 + j * 16 + laneM;
                const float bvv = bias[cl];
                const int h_ = cl >> 6;
                const int d_ = cl & 63;
                #pragma unroll
                for (int reg = 0; reg < 4; reg++) {
                    float val = acc[i][j][reg] + bvv;
                    if (seg < 2) val = (val > 0.f) ? val + 1.f : expf(val);
                    const int row = r0 + reg;
                    const int b_ = row >> 9;      // SEQ=512
                    const int n_ = row & 511;
                    outSeg[((size_t)((b_ * NHEADS + h_) * SEQ + n_)) * DK + d_] = f2bf(val);
                }
            }
        }
    } else {
        #pragma unroll
        for (int i = 0; i < 8; i++) {
            const int r0 = rowBase + wm * 128 + i * 16 + g * 4;
            #pragma unroll
            for (int j = 0; j < 4; j++) {
                const int c = colBase + wn * 64 + j * 16 + laneM;
                const float bvv = bq[c];
                #pragma unroll
                for (int reg = 0; reg < 4; reg++)
                    outF[(size_t)(r0 + reg) * 1024 + c] = acc[i][j][reg] + bvv;
            }
        }
    }
}

// ---------------------------------------------------------------------------
// Linear attention per (b,h). Inputs qf/kf/v: bf16 [B,H,N,DK].
// Output attn: bf16 [B,N,D_MODEL]. (unchanged)
// ---------------------------------------------------------------------------
__global__ __launch_bounds__(256)
void attn_kernel(const short* __restrict__ qf, const short* __restrict__ kf,
                 const short* __restrict__ v, short* __restrict__ attn)
{
    __shared__ float kfS[32][64];
    __shared__ float vS[32][64];
    __shared__ float kvS[64][68];
    __shared__ float ksumS[64];
    __shared__ float qS[64][68];

    const int bh = blockIdx.x;          // 0..511
    const int b  = bh >> 4;
    const int h  = bh & 15;
    const size_t base = (size_t)bh * SEQ * DK;
    const short* qfp = qf + base;
    const short* kfp = kf + base;
    const short* vp  = v  + base;

    const int t  = threadIdx.x;
    const int tr = t >> 4;
    const int tc = t & 15;

    float acc[4][4];
    #pragma unroll
    for (int i = 0; i < 4; i++)
        #pragma unroll
        for (int j = 0; j < 4; j++) acc[i][j] = 0.f;
    float ks[4] = {0.f, 0.f, 0.f, 0.f};

    const int lr = t >> 3;              // 0..31
    const int lc = (t & 7) * 8;         // 0..56

    for (int n0 = 0; n0 < SEQ; n0 += 32) {
        short8 k8 = *(const short8*)&kfp[(size_t)(n0 + lr) * DK + lc];
        short8 v8 = *(const short8*)&vp[(size_t)(n0 + lr) * DK + lc];
        #pragma unroll
        for (int j = 0; j < 8; j++) {
            kfS[lr][lc + j] = bf2f(k8[j]);
            vS[lr][lc + j]  = bf2f(v8[j]);
        }
        __syncthreads();
        #pragma unroll 8
        for (int nn = 0; nn < 32; nn++) {
            float a0 = kfS[nn][tr * 4 + 0];
            float a1 = kfS[nn][tr * 4 + 1];
            float a2 = kfS[nn][tr * 4 + 2];
            float a3 = kfS[nn][tr * 4 + 3];
            float4 b4 = *(float4*)&vS[nn][tc * 4];
            acc[0][0] += a0 * b4.x; acc[0][1] += a0 * b4.y; acc[0][2] += a0 * b4.z; acc[0][3] += a0 * b4.w;
            acc[1][0] += a1 * b4.x; acc[1][1] += a1 * b4.y; acc[1][2] += a1 * b4.z; acc[1][3] += a1 * b4.w;
            acc[2][0] += a2 * b4.x; acc[2][1] += a2 * b4.y; acc[2][2] += a2 * b4.z; acc[2][3] += a2 * b4.w;
            acc[3][0] += a3 * b4.x; acc[3][1] += a3 * b4.y; acc[3][2] += a3 * b4.z; acc[3][3] += a3 * b4.w;
            if (tc == 0) { ks[0] += a0; ks[1] += a1; ks[2] += a2; ks[3] += a3; }
        }
        __syncthreads();
    }

    #pragma unroll
    for (int i = 0; i < 4; i++)
        #pragma unroll
        for (int j = 0; j < 4; j++)
            kvS[tr * 4 + i][tc * 4 + j] = acc[i][j];
    if (tc == 0) {
        #pragma unroll
        for (int i = 0; i < 4; i++) ksumS[tr * 4 + i] = ks[i];
    }

    const int qlr = t >> 2;             // 0..63
    const int qlc = (t & 3) * 16;       // 0,16,32,48

    for (int n0 = 0; n0 < SEQ; n0 += 64) {
        __syncthreads();
        short8 q0 = *(const short8*)&qfp[(size_t)(n0 + qlr) * DK + qlc];
        short8 q1 = *(const short8*)&qfp[(size_t)(n0 + qlr) * DK + qlc + 8];
        #pragma unroll
        for (int j = 0; j < 8; j++) {
            qS[qlr][qlc + j]     = bf2f(q0[j]);
            qS[qlr][qlc + 8 + j] = bf2f(q1[j]);
        }
        __syncthreads();

        float4 o[4];
        float den[4];
        #pragma unroll
        for (int i = 0; i < 4; i++) {
            o[i] = make_float4(0.f, 0.f, 0.f, 0.f);
            den[i] = LIN_EPS;
        }
        #pragma unroll 4
        for (int d = 0; d < 64; d++) {
            float4 b4 = *(float4*)&kvS[d][tc * 4];
            float ksd = ksumS[d];
            #pragma unroll
            for (int i = 0; i < 4; i++) {
                float a = qS[tr * 4 + i][d];
                o[i].x += a * b4.x;
                o[i].y += a * b4.y;
                o[i].z += a * b4.z;
                o[i].w += a * b4.w;
                den[i] += a * ksd;
            }
        }
        #pragma unroll
        for (int i = 0; i < 4; i++) {
            const float inv = 1.f / den[i];
            const int n = n0 + tr * 4 + i;
            short* dst = attn + ((size_t)(b * SEQ + n)) * D_MODEL + h * DK;
            short4v s;
            s.x = f2bf(o[i].x * inv);
            s.y = f2bf(o[i].y * inv);
            s.z = f2bf(o[i].z * inv);
            s.w = f2bf(o[i].w * inv);
            *(short4v*)&dst[tc * 4] = s;
        }
    }
}

extern "C" void kernel_launch(void* const* d_in, const int* in_sizes, int n_in,
                              void* d_out, int out_size, void* d_ws, size_t ws_size,
                              hipStream_t stream)
{
    const float* x   = (const float*)d_in[0];
    const float* W_q = (const float*)d_in[1];
    const float* b_q = (const float*)d_in[2];
    const float* W_k = (const float*)d_in[3];
    const float* b_k = (const float*)d_in[4];
    const float* W_v = (const float*)d_in[5];
    const float* b_v = (const float*)d_in[6];
    const float* W_o = (const float*)d_in[7];
    const float* b_o = (const float*)d_in[8];
    float* out = (float*)d_out;

    const size_t MN = (size_t)M_TOTAL * D_MODEL;   // 16,777,216
    const size_t WN = (size_t)D_MODEL * D_MODEL;   // 1,048,576

    // Workspace: 32 + 8 + 96 + 32 = 168 MB (proven budget).
    char* ws = (char*)d_ws;
    short* xb    = (short*)ws;                 ws += MN * 2;        // 32 MB
    short* Wt    = (short*)ws;                 ws += WN * 2 * 4;    // 8 MB: q|k|v|o
    short* qkvB  = (short*)ws;                 ws += MN * 2 * 3;    // 96 MB: qf|kf|vv
    short* attnb = (short*)ws;                 ws += MN * 2;        // 32 MB

    short* Wto = Wt + WN * 3;
    short* qfb = qkvB;
    short* kfb = qkvB + MN;
    short* vvb = qkvB + MN * 2;

    cast_bf16<<<dim3((int)(MN / 4 / 256)), dim3(256), 0, stream>>>(x, xb, (int)(MN / 4));
    transpose_w4<<<dim3(32, 32, 4), dim3(32, 8), 0, stream>>>(W_q, W_k, W_v, W_o, Wt);

    // QKV: M=16384, N=3072 -> 64 x 12 = 768 blocks of 512 threads
    gemm256<0><<<dim3(768), dim3(512), 0, stream>>>(xb, Wt, b_q, b_k, b_v, qkvB, nullptr);

    attn_kernel<<<dim3(BATCH * NHEADS), dim3(256), 0, stream>>>(qfb, kfb, vvb, attnb);

    // O: M=16384, N=1024 -> 64 x 4 = 256 blocks
    gemm256<1><<<dim3(256), dim3(512), 0, stream>>>(attnb, Wto, b_o, nullptr, nullptr, nullptr, out);
}